// Round 12
// baseline (154.499 us; speedup 1.0000x reference)
//
#include <hip/hip_runtime.h>
#include <hip/hip_bf16.h>

typedef __bf16 bf16x8 __attribute__((ext_vector_type(8)));
typedef __bf16 bf16x4 __attribute__((ext_vector_type(4)));
typedef float  f32x4  __attribute__((ext_vector_type(4)));

#define MFMA16(a, b, c) __builtin_amdgcn_mfma_f32_16x16x32_bf16((a), (b), (c), 0, 0, 0)

// LDS-visibility barrier that does NOT drain outstanding global loads.
__device__ __forceinline__ void barrier_lds_only() {
    asm volatile("s_waitcnt lgkmcnt(0)" ::: "memory");
    __builtin_amdgcn_s_barrier();
    __builtin_amdgcn_sched_barrier(0);
}

// Problem constants: B=8, N=1024, D=512, H=8, DH=64

// ---------------------------------------------------------------------------
// Kernel 1: fused QKV projection (unchanged).
// ---------------------------------------------------------------------------
__global__ __launch_bounds__(256) void gemm_qkv(
    const float* __restrict__ x,
    const float* __restrict__ Wq, const float* __restrict__ Wk,
    const float* __restrict__ Wv,
    __bf16* __restrict__ qo, __bf16* __restrict__ ko, __bf16* __restrict__ vto)
{
    __shared__ __bf16 As[64][40];
    __shared__ __bf16 Bs[64][40];
    const int tid  = threadIdx.x;
    const int lane = tid & 63;
    const int wid  = tid >> 6;
    const int g    = lane >> 4, l16 = lane & 15;
    const int wr   = wid >> 1,  wc  = wid & 1;
    const int r0   = blockIdx.x * 64;
    const int widx = blockIdx.y >> 3;          // 0=q 1=k 2=v
    const int c0   = (blockIdx.y & 7) * 64;
    const float* W = (widx == 0) ? Wq : (widx == 1 ? Wk : Wv);

    const int sr  = tid >> 3;
    const int scq = tid & 7;

    f32x4 acc[2][2] = {};

    for (int k0 = 0; k0 < 512; k0 += 32) {
        __syncthreads();
#pragma unroll
        for (int j = 0; j < 2; ++j) {
            const int r = sr + 32 * j;
            float4 av = *reinterpret_cast<const float4*>(x + (size_t)(r0 + r) * 512 + k0 + scq * 4);
            float4 bv = *reinterpret_cast<const float4*>(W + (size_t)(c0 + r) * 512 + k0 + scq * 4);
            bf16x4 ap = { (__bf16)av.x, (__bf16)av.y, (__bf16)av.z, (__bf16)av.w };
            bf16x4 bp = { (__bf16)bv.x, (__bf16)bv.y, (__bf16)bv.z, (__bf16)bv.w };
            *reinterpret_cast<bf16x4*>(&As[r][scq * 4]) = ap;
            *reinterpret_cast<bf16x4*>(&Bs[r][scq * 4]) = bp;
        }
        __syncthreads();
        bf16x8 af[2], bfr[2];
#pragma unroll
        for (int rt = 0; rt < 2; ++rt)
            af[rt] = *reinterpret_cast<const bf16x8*>(&As[wr * 32 + rt * 16 + l16][g * 8]);
#pragma unroll
        for (int ct = 0; ct < 2; ++ct)
            bfr[ct] = *reinterpret_cast<const bf16x8*>(&Bs[wc * 32 + ct * 16 + l16][g * 8]);
#pragma unroll
        for (int rt = 0; rt < 2; ++rt)
#pragma unroll
            for (int ct = 0; ct < 2; ++ct)
                acc[rt][ct] = MFMA16(af[rt], bfr[ct], acc[rt][ct]);
    }

    if (widx == 2) {
#pragma unroll
        for (int rt = 0; rt < 2; ++rt)
#pragma unroll
            for (int ct = 0; ct < 2; ++ct) {
                int r = r0 + wr * 32 + rt * 16 + 4 * g;
                int c = c0 + wc * 32 + ct * 16 + l16;
                int b = r >> 10, n = r & 1023, h = c >> 6, dh = c & 63;
                bf16x4 pv = { (__bf16)acc[rt][ct][0], (__bf16)acc[rt][ct][1],
                              (__bf16)acc[rt][ct][2], (__bf16)acc[rt][ct][3] };
                *reinterpret_cast<bf16x4*>(vto + (((size_t)b * 8 + h) * 64 + dh) * 1024 + n) = pv;
            }
    } else {
        __bf16* dst = (widx == 0) ? qo : ko;
        const float scale = (widx == 0) ? 0.125f : 1.0f;
#pragma unroll
        for (int rt = 0; rt < 2; ++rt)
#pragma unroll
            for (int ct = 0; ct < 2; ++ct)
#pragma unroll
                for (int reg = 0; reg < 4; ++reg) {
                    int r = r0 + wr * 32 + rt * 16 + 4 * g + reg;
                    int c = c0 + wc * 32 + ct * 16 + l16;
                    float val = acc[rt][ct][reg] * scale;
                    int b = r >> 10, n = r & 1023, h = c >> 6, dh = c & 63;
                    dst[(((size_t)b * 8 + h) * 1024 + n) * 64 + dh] = (__bf16)val;
                }
    }
}

// ---------------------------------------------------------------------------
// Kernel 2: fused flash attention, SWAPPED QK^T (S^T = K·Q^T), 4 waves =
// 4 heads (h-half per block), 2 blocks/CU.
// - Bias: coalesced f32x4 (this half's 4 heads per load), 2-deep reg pipeline,
//   LDS [n][h][m] -> VECTOR b64 fragment reads (m is lane-contiguous now).
// - psm P-bounce: b64 vector writes / b128 reads (was 32 scalars).
// - K/V: per-wave LDS staging, coalesced global, 1-deep reg pipeline.
// - ONE lgkm-only barrier/iter; all vmcnt waits counted by compiler.
// Grid (16 = hh*8+b, 32 nt): linear%8 = b -> batch pinned to XCD.
// ---------------------------------------------------------------------------
__global__ __launch_bounds__(256) void attn_v6(
    const __bf16* __restrict__ qw, const __bf16* __restrict__ kw,
    const __bf16* __restrict__ vtw, const float* __restrict__ bias,
    __bf16* __restrict__ ow)
{
    __shared__ __bf16 Ks[4][32][72];     // [w][m][dh]  18,432 B  wave-local
    __shared__ __bf16 Vs[4][64][40];     // [w][dh][m]  20,480 B  wave-local
    __shared__ __bf16 bsm[2][32][152];   // [buf][n][w*36+m] 19,456 B
    __shared__ __bf16 psm[4][2][16][40]; // [w][rf][n16][m32+pad] 10,240 B
    __shared__ float  ls[4][32];         // denominators
    const int tid  = threadIdx.x;
    const int w    = tid >> 6;             // local wave = local head
    const int lane = tid & 63;
    const int g    = lane >> 4, l16 = lane & 15;
    const int bx   = blockIdx.x;
    const int b    = bx & 7, hh = bx >> 3;       // batch, head-half
    const int h    = hh * 4 + w;                  // global head
    const int n0   = blockIdx.y * 32;
    const size_t bhs = (size_t)b * 8 + h;

    const __bf16* kbase  = kw  + bhs * 1024 * 64;
    const __bf16* vbase  = vtw + bhs * 64 * 1024;
    const float*  bias_b = bias + ((size_t)(b * 1024 + n0)) * 8192 + hh * 4;

    const int snr = tid >> 3;     // bias stage: n-row 0..31
    const int sc  = tid & 7;      // m-chunk base

    // Q fragments (resident; used as B operand now — same data layout)
    bf16x8 qf[2][2];
#pragma unroll
    for (int rf = 0; rf < 2; ++rf)
#pragma unroll
        for (int kc = 0; kc < 2; ++kc)
            qf[rf][kc] = *reinterpret_cast<const bf16x8*>(
                qw + (bhs * 1024 + n0 + rf * 16 + l16) * 64 + kc * 32 + g * 8);

    f32x4 o[2][4] = {};
    float lsum[2] = {0.f, 0.f};

    f32x4  bpA[4], bpB[4];
    bf16x8 kp[4], vp[4];

#define LOAD_BIAS(dst, tt)                                                     \
    {                                                                          \
        const int m0_ = (tt) * 32;                                             \
        _Pragma("unroll")                                                      \
        for (int c = 0; c < 4; ++c)                                            \
            dst[c] = __builtin_nontemporal_load(reinterpret_cast<const f32x4*>(\
                bias_b + (size_t)snr * 8192 + (size_t)(m0_ + sc + 8 * c) * 8));\
    }

#define LOAD_KV(tt)                                                            \
    {                                                                          \
        const int m0_ = (tt) * 32;                                             \
        _Pragma("unroll")                                                      \
        for (int c = 0; c < 4; ++c) {                                          \
            const int idx = c * 64 + lane;                                     \
            kp[c] = *reinterpret_cast<const bf16x8*>(                          \
                kbase + (size_t)(m0_ + (idx >> 3)) * 64 + (idx & 7) * 8);      \
            vp[c] = *reinterpret_cast<const bf16x8*>(                          \
                vbase + (size_t)(idx >> 2) * 1024 + m0_ + (idx & 3) * 8);      \
        }                                                                      \
    }

#define WRITE_BIAS(buf, src)                                                   \
    {                                                                          \
        _Pragma("unroll")                                                      \
        for (int c = 0; c < 4; ++c) {                                          \
            const int mm = sc + 8 * c;                                         \
            __bf16* d = &bsm[buf][snr][mm];                                    \
            d[0]   = (__bf16)src[c].x;                                         \
            d[36]  = (__bf16)src[c].y;                                         \
            d[72]  = (__bf16)src[c].z;                                         \
            d[108] = (__bf16)src[c].w;                                         \
        }                                                                      \
    }

#define WRITE_KV()                                                             \
    {                                                                          \
        _Pragma("unroll")                                                      \
        for (int c = 0; c < 4; ++c) {                                          \
            const int idx = c * 64 + lane;                                     \
            *reinterpret_cast<bf16x8*>(&Ks[w][idx >> 3][(idx & 7) * 8]) = kp[c]; \
            *reinterpret_cast<bf16x8*>(&Vs[w][idx >> 2][(idx & 3) * 8]) = vp[c]; \
        }                                                                      \
    }

#define ATTN_STEP(t, BUF, bpX)                                                 \
    {                                                                          \
        bf16x8 kf[2][2], vf[4];                                                \
        _Pragma("unroll")                                                      \
        for (int ct = 0; ct < 2; ++ct)                                         \
            _Pragma("unroll")                                                  \
            for (int kc = 0; kc < 2; ++kc)                                     \
                kf[ct][kc] = *reinterpret_cast<const bf16x8*>(                 \
                    &Ks[w][ct * 16 + l16][kc * 32 + g * 8]);                   \
        _Pragma("unroll")                                                      \
        for (int oc = 0; oc < 4; ++oc)                                         \
            vf[oc] = *reinterpret_cast<const bf16x8*>(&Vs[w][oc * 16 + l16][g * 8]); \
        /* SWAPPED: A=K, B=Q -> lane holds S^T[m=ct*16+4g+reg][n=rf*16+l16] */ \
        f32x4 s[2][2] = {};                                                    \
        _Pragma("unroll")                                                      \
        for (int rf = 0; rf < 2; ++rf)                                         \
            _Pragma("unroll")                                                  \
            for (int ct = 0; ct < 2; ++ct) {                                   \
                s[rf][ct] = MFMA16(kf[ct][0], qf[rf][0], s[rf][ct]);           \
                s[rf][ct] = MFMA16(kf[ct][1], qf[rf][1], s[rf][ct]);           \
            }                                                                  \
        _Pragma("unroll")                                                      \
        for (int rf = 0; rf < 2; ++rf) {                                       \
            _Pragma("unroll")                                                  \
            for (int ct = 0; ct < 2; ++ct) {                                   \
                bf16x4 bb = *reinterpret_cast<const bf16x4*>(                  \
                    &bsm[BUF][rf * 16 + l16][w * 36 + ct * 16 + 4 * g]);       \
                bf16x4 pw;                                                     \
                _Pragma("unroll")                                              \
                for (int reg = 0; reg < 4; ++reg) {                            \
                    float p = __expf(s[rf][ct][reg] + (float)bb[reg] - 16.0f); \
                    lsum[rf] += p;                                             \
                    pw[reg] = (__bf16)p;                                       \
                }                                                              \
                *reinterpret_cast<bf16x4*>(                                    \
                    &psm[w][rf][l16][ct * 16 + 4 * g]) = pw;                   \
            }                                                                  \
        }                                                                      \
        /* wave-local vector P relayout + PV (orientation unchanged) */        \
        bf16x8 pf[2];                                                          \
        asm volatile("s_waitcnt lgkmcnt(0)" ::: "memory");                     \
        __builtin_amdgcn_sched_barrier(0);                                     \
        _Pragma("unroll")                                                      \
        for (int rf = 0; rf < 2; ++rf)                                         \
            pf[rf] = *reinterpret_cast<const bf16x8*>(&psm[w][rf][l16][g * 8]); \
        _Pragma("unroll")                                                      \
        for (int rf = 0; rf < 2; ++rf)                                         \
            _Pragma("unroll")                                                  \
            for (int oc = 0; oc < 4; ++oc)                                     \
                o[rf][oc] = MFMA16(pf[rf], vf[oc], o[rf][oc]);                 \
        /* stage tile t+1 (all waits counted: bias 2-deep, K/V 1-deep) */      \
        WRITE_BIAS((BUF) ^ 1, bpX)                                             \
        WRITE_KV()                                                             \
        LOAD_KV((t) + 2 < 32 ? (t) + 2 : 31)                                   \
        LOAD_BIAS(bpX, (t) + 3 < 32 ? (t) + 3 : 31)                            \
        barrier_lds_only();                                                    \
    }

    // ---- prologue ----
    LOAD_BIAS(bpA, 0)
    LOAD_KV(0)
    WRITE_BIAS(0, bpA)
    WRITE_KV()
    LOAD_KV(1)
    LOAD_BIAS(bpA, 1)
    LOAD_BIAS(bpB, 2)
    __syncthreads();

    for (int t = 0; t < 32; t += 2) {
        ATTN_STEP(t,     0, bpA)
        ATTN_STEP(t + 1, 1, bpB)
    }
#undef ATTN_STEP
#undef LOAD_BIAS
#undef LOAD_KV
#undef WRITE_BIAS
#undef WRITE_KV

    // epilogue: lsum[rf] is partial over this lane's 8 m-values for n=rf*16+l16;
    // reduce across the 4 g-replicas, publish via LDS, renormalize outputs.
#pragma unroll
    for (int rf = 0; rf < 2; ++rf) {
        float l = lsum[rf];
        l += __shfl_xor(l, 16);
        l += __shfl_xor(l, 32);
        if (lane < 16) ls[w][rf * 16 + l16] = l;
    }
#pragma unroll
    for (int rf = 0; rf < 2; ++rf)
#pragma unroll
        for (int reg = 0; reg < 4; ++reg) {
            float linv = 1.0f / ls[w][rf * 16 + 4 * g + reg];
#pragma unroll
            for (int oc = 0; oc < 4; ++oc) {
                int n  = n0 + rf * 16 + 4 * g + reg;
                int dh = oc * 16 + l16;
                ow[((size_t)b * 1024 + n) * 512 + h * 64 + dh] =
                    (__bf16)(o[rf][oc][reg] * linv);
            }
        }
}

// ---------------------------------------------------------------------------
// Kernel 3: output projection (unchanged).
// ---------------------------------------------------------------------------
__global__ __launch_bounds__(256) void gemm_out(
    const __bf16* __restrict__ a, const float* __restrict__ Wm,
    const float* __restrict__ bm, float* __restrict__ out)
{
    __shared__ __bf16 As[64][40];
    __shared__ __bf16 Bs[64][40];
    const int tid  = threadIdx.x;
    const int lane = tid & 63;
    const int wid  = tid >> 6;
    const int g    = lane >> 4, l16 = lane & 15;
    const int wr   = wid >> 1,  wc  = wid & 1;
    const int r0   = blockIdx.x * 64;
    const int c0   = blockIdx.y * 64;

    const int sra = tid >> 2, sca = tid & 3;
    const int srb = tid >> 3, scb = tid & 7;

    f32x4 acc[2][2] = {};
    for (int k0 = 0; k0 < 512; k0 += 32) {
        __syncthreads();
        {
            bf16x8 av = *reinterpret_cast<const bf16x8*>(a + (size_t)(r0 + sra) * 512 + k0 + sca * 8);
            *reinterpret_cast<bf16x8*>(&As[sra][sca * 8]) = av;
#pragma unroll
            for (int j = 0; j < 2; ++j) {
                int r = srb + 32 * j;
                float4 bv = *reinterpret_cast<const float4*>(Wm + (size_t)(c0 + r) * 512 + k0 + scb * 4);
                bf16x4 bp = { (__bf16)bv.x, (__bf16)bv.y, (__bf16)bv.z, (__bf16)bv.w };
                *reinterpret_cast<bf16x4*>(&Bs[r][scb * 4]) = bp;
            }
        }
        __syncthreads();
        bf16x8 af[2], bfr[2];
#pragma unroll
        for (int rt = 0; rt < 2; ++rt)
            af[rt] = *reinterpret_cast<const bf16x8*>(&As[wr * 32 + rt * 16 + l16][g * 8]);
#pragma unroll
        for (int ct = 0; ct < 2; ++ct)
            bfr[ct] = *reinterpret_cast<const bf16x8*>(&Bs[wc * 32 + ct * 16 + l16][g * 8]);
#pragma unroll
        for (int rt = 0; rt < 2; ++rt)
#pragma unroll
            for (int ct = 0; ct < 2; ++ct)
                acc[rt][ct] = MFMA16(af[rt], bfr[ct], acc[rt][ct]);
    }

#pragma unroll
    for (int rt = 0; rt < 2; ++rt)
#pragma unroll
        for (int ct = 0; ct < 2; ++ct)
#pragma unroll
            for (int reg = 0; reg < 4; ++reg) {
                int r = r0 + wr * 32 + rt * 16 + 4 * g + reg;
                int c = c0 + wc * 32 + ct * 16 + l16;
                out[(size_t)r * 512 + c] = acc[rt][ct][reg] + bm[c];
            }
}

// ---------------------------------------------------------------------------
extern "C" void kernel_launch(void* const* d_in, const int* in_sizes, int n_in,
                              void* d_out, int out_size, void* d_ws, size_t ws_size,
                              hipStream_t stream)
{
    const float* x    = (const float*)d_in[0];
    const float* bias = (const float*)d_in[1];
    const float* Wq   = (const float*)d_in[2];
    const float* Wk   = (const float*)d_in[3];
    const float* Wv   = (const float*)d_in[4];
    const float* Wm   = (const float*)d_in[5];
    const float* bm   = (const float*)d_in[6];
    float* out = (float*)d_out;

    const size_t SEG = (size_t)8 * 8 * 1024 * 64;   // 4M elems (8 MB bf16) each
    __bf16* qw  = (__bf16*)d_ws;
    __bf16* kw  = qw + SEG;
    __bf16* vtw = kw + SEG;
    __bf16* ow  = vtw + SEG;

    gemm_qkv<<<dim3(128, 24), 256, 0, stream>>>(x, Wq, Wk, Wv, qw, kw, vtw);
    attn_v6 <<<dim3(16, 32), 256, 0, stream>>>(qw, kw, vtw, bias, ow);
    gemm_out<<<dim3(128, 8), 256, 0, stream>>>(ow, Wm, bm, out);
}

// Round 13
// 137.855 us; speedup vs baseline: 1.1207x; 1.1207x over previous
//
#include <hip/hip_runtime.h>
#include <hip/hip_bf16.h>

typedef __bf16 bf16x8 __attribute__((ext_vector_type(8)));
typedef __bf16 bf16x4 __attribute__((ext_vector_type(4)));
typedef float  f32x4  __attribute__((ext_vector_type(4)));

#define MFMA16(a, b, c) __builtin_amdgcn_mfma_f32_16x16x32_bf16((a), (b), (c), 0, 0, 0)

typedef const __attribute__((address_space(1))) unsigned int* gas_t;
typedef __attribute__((address_space(3))) unsigned int* las_t;
// DMA global->LDS, 16B/lane, linear LDS dest (base + lane*16).
__device__ __forceinline__ void dma16(const __bf16* g, __bf16* l) {
    __builtin_amdgcn_global_load_lds((gas_t)g, (las_t)l, 16, 0, 0);
}

// Problem constants: B=8, N=1024, D=512, H=8, DH=64

// ---------------------------------------------------------------------------
// Kernel 1: fused QKV projection — ONE pass over x serves all 3 weights.
// q,k: [b][h][n][dh] bf16 (q pre-scaled 0.125); v: [b][h][dh][n] bf16.
// ---------------------------------------------------------------------------
__global__ __launch_bounds__(256) void gemm_qkv(
    const float* __restrict__ x,
    const float* __restrict__ Wq, const float* __restrict__ Wk,
    const float* __restrict__ Wv,
    __bf16* __restrict__ qo, __bf16* __restrict__ ko, __bf16* __restrict__ vto)
{
    __shared__ __bf16 As[64][40];
    __shared__ __bf16 Bs[3][64][40];
    const int tid  = threadIdx.x;
    const int lane = tid & 63;
    const int wid  = tid >> 6;
    const int g    = lane >> 4, l16 = lane & 15;
    const int wr   = wid >> 1,  wc  = wid & 1;
    const int r0   = blockIdx.x * 64;
    const int c0   = blockIdx.y * 64;
    const float* Ws[3] = { Wq, Wk, Wv };

    const int sr  = tid >> 3;
    const int scq = tid & 7;

    f32x4 acc[3][2][2] = {};

    for (int k0 = 0; k0 < 512; k0 += 32) {
        __syncthreads();
#pragma unroll
        for (int j = 0; j < 2; ++j) {
            const int r = sr + 32 * j;
            float4 av = *reinterpret_cast<const float4*>(x + (size_t)(r0 + r) * 512 + k0 + scq * 4);
            bf16x4 ap = { (__bf16)av.x, (__bf16)av.y, (__bf16)av.z, (__bf16)av.w };
            *reinterpret_cast<bf16x4*>(&As[r][scq * 4]) = ap;
#pragma unroll
            for (int widx = 0; widx < 3; ++widx) {
                float4 bv = *reinterpret_cast<const float4*>(Ws[widx] + (size_t)(c0 + r) * 512 + k0 + scq * 4);
                bf16x4 bp = { (__bf16)bv.x, (__bf16)bv.y, (__bf16)bv.z, (__bf16)bv.w };
                *reinterpret_cast<bf16x4*>(&Bs[widx][r][scq * 4]) = bp;
            }
        }
        __syncthreads();
        bf16x8 af[2];
#pragma unroll
        for (int rt = 0; rt < 2; ++rt)
            af[rt] = *reinterpret_cast<const bf16x8*>(&As[wr * 32 + rt * 16 + l16][g * 8]);
#pragma unroll
        for (int widx = 0; widx < 3; ++widx) {
            bf16x8 bfr[2];
#pragma unroll
            for (int ct = 0; ct < 2; ++ct)
                bfr[ct] = *reinterpret_cast<const bf16x8*>(&Bs[widx][wc * 32 + ct * 16 + l16][g * 8]);
#pragma unroll
            for (int rt = 0; rt < 2; ++rt)
#pragma unroll
                for (int ct = 0; ct < 2; ++ct)
                    acc[widx][rt][ct] = MFMA16(af[rt], bfr[ct], acc[widx][rt][ct]);
        }
    }

    // q, k: [b][h][n][dh]
#pragma unroll
    for (int widx = 0; widx < 2; ++widx) {
        __bf16* dst = (widx == 0) ? qo : ko;
        const float scale = (widx == 0) ? 0.125f : 1.0f;
#pragma unroll
        for (int rt = 0; rt < 2; ++rt)
#pragma unroll
            for (int ct = 0; ct < 2; ++ct)
#pragma unroll
                for (int reg = 0; reg < 4; ++reg) {
                    int r = r0 + wr * 32 + rt * 16 + 4 * g + reg;
                    int c = c0 + wc * 32 + ct * 16 + l16;
                    float val = acc[widx][rt][ct][reg] * scale;
                    int b = r >> 10, n = r & 1023, h = c >> 6, dh = c & 63;
                    dst[(((size_t)b * 8 + h) * 1024 + n) * 64 + dh] = (__bf16)val;
                }
    }
    // v transposed: [b][h][dh][n]
#pragma unroll
    for (int rt = 0; rt < 2; ++rt)
#pragma unroll
        for (int ct = 0; ct < 2; ++ct) {
            int r = r0 + wr * 32 + rt * 16 + 4 * g;
            int c = c0 + wc * 32 + ct * 16 + l16;
            int b = r >> 10, n = r & 1023, h = c >> 6, dh = c & 63;
            bf16x4 pv = { (__bf16)acc[2][rt][ct][0], (__bf16)acc[2][rt][ct][1],
                          (__bf16)acc[2][rt][ct][2], (__bf16)acc[2][rt][ct][3] };
            *reinterpret_cast<bf16x4*>(vto + (((size_t)b * 8 + h) * 64 + dh) * 1024 + n) = pv;
        }
}

// ---------------------------------------------------------------------------
// Kernel 2: fused flash attention v7.
// 8 waves = 8 heads, 32 Q-rows, grid (8 b, 32 nt).
// - K/V staged via global_load_lds (no reg round-trip, no ds_writes);
//   K source-XOR-swizzled (chunk ^= m&7) for conflict-free b128 reads;
//   single-buffered (wave-local), drained by counted vmcnt(4).
// - Bias: coalesced f32x4 nt loads, 2-deep reg pipeline, LDS [h][m][n36]
//   -> 4x b64 fragment reads (n is reg-contiguous).
// - Fixed-max softmax p = exp(s+bias-16); ONE lgkm-only barrier/iter.
// ---------------------------------------------------------------------------
__global__ __launch_bounds__(512, 2) void attn_v7(
    const __bf16* __restrict__ qw, const __bf16* __restrict__ kw,
    const __bf16* __restrict__ vtw, const float* __restrict__ bias,
    __bf16* __restrict__ ow)
{
    __shared__ __align__(16) __bf16 Ks[8][32][64];     // 32 KB, swizzled content
    __shared__ __align__(16) __bf16 Vs[8][64][32];     // 32 KB, [dh][m] linear
    __shared__ __align__(16) __bf16 bsm[2][8][32][36]; // 36.9 KB, [buf][h][m][n]
    __shared__ __bf16 psm[8][32][40];                  // 20.5 KB
    const int tid  = threadIdx.x;
    const int w    = tid >> 6;             // head
    const int lane = tid & 63;
    const int g    = lane >> 4, l16 = lane & 15;
    const int b    = blockIdx.x;
    const int n0   = blockIdx.y * 32;
    const size_t bhs = (size_t)b * 8 + w;

    const __bf16* kbase  = kw  + bhs * 1024 * 64;
    const __bf16* vbase  = vtw + bhs * 64 * 1024;
    const float*  bias_b = bias + ((size_t)(b * 1024 + n0)) * 8192;

    const int snr = tid >> 4;     // bias n-row 0..31
    const int sf  = tid & 15;     // bias f32x4 chunk base

    // per-lane DMA source offsets (constant across tiles)
    const int k_row  = lane >> 3;                       // row within 8-row block
    const int k_csrc = (lane & 7) ^ (k_row & 7);        // swizzled source chunk
    const int v_row  = lane >> 2;                       // dh within 16-row block
    const int v_mc   = lane & 3;

    bf16x8 qf[2][2];
#pragma unroll
    for (int rf = 0; rf < 2; ++rf)
#pragma unroll
        for (int kc = 0; kc < 2; ++kc)
            qf[rf][kc] = *reinterpret_cast<const bf16x8*>(
                qw + (bhs * 1024 + n0 + rf * 16 + l16) * 64 + kc * 32 + g * 8);

    f32x4 o[2][4] = {};
    float lrun[2][4] = {};

    f32x4 bpA[4], bpB[4];

#define LOAD_BIAS(dst, tt)                                                     \
    {                                                                          \
        const int m0_ = (tt) * 32;                                             \
        _Pragma("unroll")                                                      \
        for (int c = 0; c < 4; ++c)                                            \
            dst[c] = __builtin_nontemporal_load(reinterpret_cast<const f32x4*>(\
                bias_b + (size_t)snr * 8192 + m0_ * 8 + (sf + 16 * c) * 4));   \
    }

#define WRITE_BIAS(buf, src)                                                   \
    {                                                                          \
        _Pragma("unroll")                                                      \
        for (int c = 0; c < 4; ++c) {                                          \
            const int f4 = sf + 16 * c;                                        \
            const int mm = f4 >> 1, h0 = (f4 & 1) * 4;                         \
            bsm[buf][h0 + 0][mm][snr] = (__bf16)src[c].x;                      \
            bsm[buf][h0 + 1][mm][snr] = (__bf16)src[c].y;                      \
            bsm[buf][h0 + 2][mm][snr] = (__bf16)src[c].z;                      \
            bsm[buf][h0 + 3][mm][snr] = (__bf16)src[c].w;                      \
        }                                                                      \
    }

#define DMA_KV(tt)                                                             \
    {                                                                          \
        const int m0_ = (tt) * 32;                                             \
        _Pragma("unroll")                                                      \
        for (int i = 0; i < 4; ++i)                                            \
            dma16(kbase + (size_t)(m0_ + i * 8 + k_row) * 64 + k_csrc * 8,     \
                  &Ks[w][i * 8][0]);                                           \
        _Pragma("unroll")                                                      \
        for (int i = 0; i < 4; ++i)                                            \
            dma16(vbase + (size_t)(i * 16 + v_row) * 1024 + m0_ + v_mc * 8,    \
                  &Vs[w][i * 16][0]);                                          \
    }

    // ---- prologue ----
    LOAD_BIAS(bpA, 0)
    DMA_KV(0)
    WRITE_BIAS(0, bpA)
    LOAD_BIAS(bpA, 1)
    LOAD_BIAS(bpB, 2)
    asm volatile("s_waitcnt vmcnt(8)");   // drain DMAs, keep bpA/bpB in flight
    __builtin_amdgcn_sched_barrier(0);
    asm volatile("s_waitcnt lgkmcnt(0)");
    __builtin_amdgcn_s_barrier();
    __builtin_amdgcn_sched_barrier(0);

#define ATTN_STEP(t, BUF, bpX)                                                 \
    {                                                                          \
        /* fragment reads: K swizzled, V linear, bias b64 */                   \
        bf16x8 kf[2][2], vf[4];                                                \
        _Pragma("unroll")                                                      \
        for (int ct = 0; ct < 2; ++ct)                                         \
            _Pragma("unroll")                                                  \
            for (int kc = 0; kc < 2; ++kc) {                                   \
                const int mrow = ct * 16 + l16;                                \
                kf[ct][kc] = *reinterpret_cast<const bf16x8*>(                 \
                    &Ks[w][mrow][(((kc * 4 + g) ^ (l16 & 7)) * 8)]);           \
            }                                                                  \
        _Pragma("unroll")                                                      \
        for (int oc = 0; oc < 4; ++oc)                                         \
            vf[oc] = *reinterpret_cast<const bf16x8*>(&Vs[w][oc * 16 + l16][g * 8]); \
        bf16x4 bb[2][2];                                                       \
        _Pragma("unroll")                                                      \
        for (int rf = 0; rf < 2; ++rf)                                         \
            _Pragma("unroll")                                                  \
            for (int ct = 0; ct < 2; ++ct)                                     \
                bb[rf][ct] = *reinterpret_cast<const bf16x4*>(                 \
                    &bsm[BUF][w][ct * 16 + l16][rf * 16 + 4 * g]);             \
        /* all LDS reads retired before DMA may overwrite Ks/Vs */             \
        asm volatile("s_waitcnt lgkmcnt(0)");                                  \
        __builtin_amdgcn_sched_barrier(0);                                     \
        DMA_KV((t) + 1 < 32 ? (t) + 1 : 31)                                    \
        /* QK^T */                                                             \
        f32x4 s[2][2] = {};                                                    \
        _Pragma("unroll")                                                      \
        for (int rf = 0; rf < 2; ++rf)                                         \
            _Pragma("unroll")                                                  \
            for (int ct = 0; ct < 2; ++ct) {                                   \
                s[rf][ct] = MFMA16(qf[rf][0], kf[ct][0], s[rf][ct]);           \
                s[rf][ct] = MFMA16(qf[rf][1], kf[ct][1], s[rf][ct]);           \
            }                                                                  \
        /* fixed-max softmax */                                                \
        _Pragma("unroll")                                                      \
        for (int rf = 0; rf < 2; ++rf)                                         \
            _Pragma("unroll")                                                  \
            for (int reg = 0; reg < 4; ++reg) {                                \
                const int nr = rf * 16 + 4 * g + reg;                          \
                float p0 = __expf(s[rf][0][reg] + (float)bb[rf][0][reg] - 16.0f); \
                float p1 = __expf(s[rf][1][reg] + (float)bb[rf][1][reg] - 16.0f); \
                lrun[rf][reg] += p0 + p1;                                      \
                psm[w][nr][l16]      = (__bf16)p0;                             \
                psm[w][nr][16 + l16] = (__bf16)p1;                             \
            }                                                                  \
        bf16x8 pf[2];                                                          \
        _Pragma("unroll")                                                      \
        for (int rf = 0; rf < 2; ++rf)                                         \
            pf[rf] = *reinterpret_cast<const bf16x8*>(&psm[w][rf * 16 + l16][g * 8]); \
        _Pragma("unroll")                                                      \
        for (int rf = 0; rf < 2; ++rf)                                         \
            _Pragma("unroll")                                                  \
            for (int oc = 0; oc < 4; ++oc)                                     \
                o[rf][oc] = MFMA16(pf[rf], vf[oc], o[rf][oc]);                 \
        /* stage next bias tile; refill its reg set (2-deep) */                \
        WRITE_BIAS((BUF) ^ 1, bpX)                                             \
        LOAD_BIAS(bpX, (t) + 3 < 32 ? (t) + 3 : 31)                            \
        /* drain this iter's DMAs (keep the 4 newest bias loads) */            \
        asm volatile("s_waitcnt vmcnt(4)");                                    \
        __builtin_amdgcn_sched_barrier(0);                                     \
        asm volatile("s_waitcnt lgkmcnt(0)");                                  \
        __builtin_amdgcn_s_barrier();                                          \
        __builtin_amdgcn_sched_barrier(0);                                     \
    }

    for (int t = 0; t < 32; t += 2) {
        ATTN_STEP(t,     0, bpA)
        ATTN_STEP(t + 1, 1, bpB)
    }
#undef ATTN_STEP
#undef LOAD_BIAS
#undef WRITE_BIAS
#undef DMA_KV

    // epilogue: denominator across the 16 m-lanes
#pragma unroll
    for (int rf = 0; rf < 2; ++rf)
#pragma unroll
        for (int reg = 0; reg < 4; ++reg) {
            float l = lrun[rf][reg];
            l += __shfl_xor(l, 1);
            l += __shfl_xor(l, 2);
            l += __shfl_xor(l, 4);
            l += __shfl_xor(l, 8);
            lrun[rf][reg] = l;
        }

#pragma unroll
    for (int rf = 0; rf < 2; ++rf)
#pragma unroll
        for (int oc = 0; oc < 4; ++oc)
#pragma unroll
            for (int reg = 0; reg < 4; ++reg) {
                int n  = n0 + rf * 16 + 4 * g + reg;
                int dh = oc * 16 + l16;
                float val = o[rf][oc][reg] / lrun[rf][reg];
                ow[((size_t)b * 1024 + n) * 512 + w * 64 + dh] = (__bf16)val;
            }
}

// ---------------------------------------------------------------------------
// Kernel 3: output projection (unchanged).
// ---------------------------------------------------------------------------
__global__ __launch_bounds__(256) void gemm_out(
    const __bf16* __restrict__ a, const float* __restrict__ Wm,
    const float* __restrict__ bm, float* __restrict__ out)
{
    __shared__ __bf16 As[64][40];
    __shared__ __bf16 Bs[64][40];
    const int tid  = threadIdx.x;
    const int lane = tid & 63;
    const int wid  = tid >> 6;
    const int g    = lane >> 4, l16 = lane & 15;
    const int wr   = wid >> 1,  wc  = wid & 1;
    const int r0   = blockIdx.x * 64;
    const int c0   = blockIdx.y * 64;

    const int sra = tid >> 2, sca = tid & 3;
    const int srb = tid >> 3, scb = tid & 7;

    f32x4 acc[2][2] = {};
    for (int k0 = 0; k0 < 512; k0 += 32) {
        __syncthreads();
        {
            bf16x8 av = *reinterpret_cast<const bf16x8*>(a + (size_t)(r0 + sra) * 512 + k0 + sca * 8);
            *reinterpret_cast<bf16x8*>(&As[sra][sca * 8]) = av;
#pragma unroll
            for (int j = 0; j < 2; ++j) {
                int r = srb + 32 * j;
                float4 bv = *reinterpret_cast<const float4*>(Wm + (size_t)(c0 + r) * 512 + k0 + scb * 4);
                bf16x4 bp = { (__bf16)bv.x, (__bf16)bv.y, (__bf16)bv.z, (__bf16)bv.w };
                *reinterpret_cast<bf16x4*>(&Bs[r][scb * 4]) = bp;
            }
        }
        __syncthreads();
        bf16x8 af[2], bfr[2];
#pragma unroll
        for (int rt = 0; rt < 2; ++rt)
            af[rt] = *reinterpret_cast<const bf16x8*>(&As[wr * 32 + rt * 16 + l16][g * 8]);
#pragma unroll
        for (int ct = 0; ct < 2; ++ct)
            bfr[ct] = *reinterpret_cast<const bf16x8*>(&Bs[wc * 32 + ct * 16 + l16][g * 8]);
#pragma unroll
        for (int rt = 0; rt < 2; ++rt)
#pragma unroll
            for (int ct = 0; ct < 2; ++ct)
                acc[rt][ct] = MFMA16(af[rt], bfr[ct], acc[rt][ct]);
    }

#pragma unroll
    for (int rt = 0; rt < 2; ++rt)
#pragma unroll
        for (int ct = 0; ct < 2; ++ct)
#pragma unroll
            for (int reg = 0; reg < 4; ++reg) {
                int r = r0 + wr * 32 + rt * 16 + 4 * g + reg;
                int c = c0 + wc * 32 + ct * 16 + l16;
                out[(size_t)r * 512 + c] = acc[rt][ct][reg] + bm[c];
            }
}

// ---------------------------------------------------------------------------
extern "C" void kernel_launch(void* const* d_in, const int* in_sizes, int n_in,
                              void* d_out, int out_size, void* d_ws, size_t ws_size,
                              hipStream_t stream)
{
    const float* x    = (const float*)d_in[0];
    const float* bias = (const float*)d_in[1];
    const float* Wq   = (const float*)d_in[2];
    const float* Wk   = (const float*)d_in[3];
    const float* Wv   = (const float*)d_in[4];
    const float* Wm   = (const float*)d_in[5];
    const float* bm   = (const float*)d_in[6];
    float* out = (float*)d_out;

    const size_t SEG = (size_t)8 * 8 * 1024 * 64;   // 4M elems (8 MB bf16) each
    __bf16* qw  = (__bf16*)d_ws;
    __bf16* kw  = qw + SEG;
    __bf16* vtw = kw + SEG;
    __bf16* ow  = vtw + SEG;

    gemm_qkv<<<dim3(128, 8), 256, 0, stream>>>(x, Wq, Wk, Wv, qw, kw, vtw);
    attn_v7 <<<dim3(8, 32), 512, 0, stream>>>(qw, kw, vtw, bias, ow);
    gemm_out<<<dim3(128, 8), 256, 0, stream>>>(ow, Wm, bm, out);
}